// Round 1
// baseline (656.126 us; speedup 1.0000x reference)
//
#include <hip/hip_runtime.h>
#include <stdint.h>

#define GW 1024
#define GH 1024
#define NPIX (GW*GH)
#define MAXC 131072
#define KMAX 8192

// state bits
#define A_DEC  1
#define A_KEPT 2
#define B_DEC  4
#define B_KEPT 8
#define C_DEC  16
#define C_KEPT 32

__global__ void k_init(unsigned int* mm) {
  if (threadIdx.x == 0) {
    mm[0] = 0u;            // candidate count
    mm[1] = 0x7F800000u;   // rmin bits (+inf)
    mm[2] = 0u;            // rmax bits
    mm[3] = 0u;            // bmax bits
  }
}

__global__ void k_resid(const float4* __restrict__ x1, const float4* __restrict__ x2,
                        const float4* __restrict__ x3, float4* __restrict__ r,
                        unsigned int* __restrict__ mm) {
  const int N4 = NPIX / 4;
  int t = blockIdx.x * blockDim.x + threadIdx.x;
  float4 s1 = make_float4(0.f,0.f,0.f,0.f);
  float4 s2 = make_float4(0.f,0.f,0.f,0.f);
#pragma unroll
  for (int c = 0; c < 8; ++c) {
    float4 a = x1[c*N4 + t];
    float4 b = x2[c*N4 + t];
    float4 d = x3[c*N4 + t];
    s1.x += fabsf(a.x-b.x); s1.y += fabsf(a.y-b.y);
    s1.z += fabsf(a.z-b.z); s1.w += fabsf(a.w-b.w);
    s2.x += fabsf(b.x-d.x); s2.y += fabsf(b.y-d.y);
    s2.z += fabsf(b.z-d.z); s2.w += fabsf(b.w-d.w);
  }
  float4 rv = make_float4((s1.x+s2.x)*0.5f, (s1.y+s2.y)*0.5f,
                          (s1.z+s2.z)*0.5f, (s1.w+s2.w)*0.5f);
  r[t] = rv;
  float mn = fminf(fminf(rv.x,rv.y), fminf(rv.z,rv.w));
  float mx = fmaxf(fmaxf(rv.x,rv.y), fmaxf(rv.z,rv.w));
#pragma unroll
  for (int o = 32; o > 0; o >>= 1) {
    mn = fminf(mn, __shfl_down(mn, o));
    mx = fmaxf(mx, __shfl_down(mx, o));
  }
  if ((threadIdx.x & 63) == 0) {
    atomicMin(&mm[1], __float_as_uint(mn));
    atomicMax(&mm[2], __float_as_uint(mx));
  }
}

// y-direction ROI-align interp (normalize r inline), exact _interp1d semantics
__global__ void k_convy(const float* __restrict__ r, float* __restrict__ A,
                        const unsigned int* __restrict__ mm) {
  int x = blockIdx.x * 256 + threadIdx.x;
  int y = blockIdx.y;
  float rmin = __uint_as_float(mm[1]);
  float denom = __uint_as_float(mm[2]) - rmin + 1e-6f;
  const float offs[4] = {-1.5f, -0.5f, 0.5f, 1.5f};
  float a = 0.f, b = 0.f;
#pragma unroll
  for (int k = 0; k < 4; ++k) {
    float c = (float)y + offs[k];
    bool valid = (c >= -1.0f) && (c <= (float)GH);
    float cc = fminf(fmaxf(c, 0.0f), (float)(GH - 1));
    int lo = (int)floorf(cc);
    int hi = min(lo + 1, GH - 1);
    float frac = cc - (float)lo;
    float w0 = valid ? 1.0f - frac : 0.0f;
    float w1 = valid ? frac : 0.0f;
    a += ((r[lo*GW + x] - rmin) / denom) * w0;
    b += ((r[hi*GW + x] - rmin) / denom) * w1;
  }
  A[y*GW + x] = a + b;
}

// x-direction interp, /16, and global max of B
__global__ void k_convx(const float* __restrict__ A, float* __restrict__ B,
                        unsigned int* __restrict__ mm) {
  int x = blockIdx.x * 256 + threadIdx.x;
  int y = blockIdx.y;
  const float offs[4] = {-1.5f, -0.5f, 0.5f, 1.5f};
  float a = 0.f, b = 0.f;
#pragma unroll
  for (int k = 0; k < 4; ++k) {
    float c = (float)x + offs[k];
    bool valid = (c >= -1.0f) && (c <= (float)GW);
    float cc = fminf(fmaxf(c, 0.0f), (float)(GW - 1));
    int lo = (int)floorf(cc);
    int hi = min(lo + 1, GW - 1);
    float frac = cc - (float)lo;
    float w0 = valid ? 1.0f - frac : 0.0f;
    float w1 = valid ? frac : 0.0f;
    a += A[y*GW + lo] * w0;
    b += A[y*GW + hi] * w1;
  }
  float v = (a + b) * 0.0625f;   // /16 exact
  B[y*GW + x] = v;
  float mx = v;
#pragma unroll
  for (int o = 32; o > 0; o >>= 1) mx = fmaxf(mx, __shfl_down(mx, o));
  if ((threadIdx.x & 63) == 0) atomicMax(&mm[3], __float_as_uint(mx));
}

// normalize by max, store score map, zero state, build candidate list
__global__ void k_cand(const float* __restrict__ B, float* __restrict__ score,
                       uint8_t* __restrict__ state, unsigned int* __restrict__ list,
                       unsigned int* __restrict__ mm) {
  int p = blockIdx.x * 256 + threadIdx.x;
  float bmax = __uint_as_float(mm[3]);
  float l = B[p] / (bmax + 1e-6f);
  score[p] = l;
  state[p] = 0;
  if (l > 0.90f && !(l == 0.95f)) {
    unsigned int i = atomicAdd(&mm[0], 1u);
    if (i < MAXC) list[i] = (unsigned int)p;
  }
}

// Single-block fixed-point greedy NMS (3 stages) + sort + output
__global__ __launch_bounds__(1024) void k_nms(const float* __restrict__ score,
                                              uint8_t* __restrict__ state,
                                              const unsigned int* __restrict__ list,
                                              const unsigned int* __restrict__ mm,
                                              float* __restrict__ out, int nrows) {
  __shared__ uint8_t buf[131072];           // bitmap (rounds) then keys (sort)
  __shared__ int s_changed, s_undec;
  __shared__ unsigned int s_k;
  unsigned int* bitmap = (unsigned int*)buf;
  unsigned long long* keys = (unsigned long long*)buf;
  const int tid = threadIdx.x;
  int M = (int)min(mm[0], (unsigned int)MAXC);

  for (int i = tid; i < 32768; i += 1024) bitmap[i] = 0u;
  __syncthreads();
  for (int i = tid; i < M; i += 1024) {
    unsigned int p = list[i];
    atomicOr(&bitmap[p >> 5], 1u << (p & 31));
  }
  __syncthreads();

  // ---- Stage A (high band, inter>=2) and Stage B (low band, inter>=3), independent
  for (int iter = 0; iter < 100000; ++iter) {
    if (tid == 0) { s_changed = 0; s_undec = 0; }
    __syncthreads();
    for (int i = tid; i < M; i += 1024) {
      unsigned int pos = list[i];
      uint8_t st = state[pos];
      float s = score[pos];
      bool high = (s > 0.95f);
      uint8_t DEC = high ? (uint8_t)A_DEC : (uint8_t)B_DEC;
      uint8_t KPT = high ? (uint8_t)A_KEPT : (uint8_t)B_KEPT;
      if (st & DEC) continue;
      int thr = high ? 2 : 3;
      int y = (int)(pos >> 10), x = (int)(pos & 1023);
      bool sup = false, undec = false;
      for (int dy = -3; dy <= 3 && !sup; ++dy) {
        int ny = y + dy;
        if ((unsigned)ny >= (unsigned)GH) continue;
        int ady = dy < 0 ? -dy : dy;
        int wy = 4 - ady;
        for (int dx = -3; dx <= 3; ++dx) {
          if ((dx | dy) == 0) continue;
          int adx = dx < 0 ? -dx : dx;
          if ((4 - adx) * wy < thr) continue;
          int nx = x + dx;
          if ((unsigned)nx >= (unsigned)GW) continue;
          unsigned int np = (unsigned int)(ny*GW + nx);
          if (!((bitmap[np >> 5] >> (np & 31)) & 1u)) continue;
          float ns = score[np];
          if (high) { if (!(ns > 0.95f)) continue; }
          else      { if (!(ns > 0.90f && ns < 0.95f)) continue; }
          if (!(ns > s || (ns == s && np < pos))) continue;   // priority
          uint8_t nst = state[np];
          if (nst & KPT) { sup = true; break; }
          if (!(nst & DEC)) undec = true;
        }
      }
      if (sup)            { state[pos] = st | DEC;        s_changed = 1; }
      else if (!undec)    { state[pos] = st | DEC | KPT;  s_changed = 1; }
      else                s_undec = 1;
    }
    __syncthreads();
    int chg = s_changed, und = s_undec;
    __syncthreads();
    if (!und || !chg) break;
  }
  __syncthreads();

  // ---- Stage C: B-kept lows, inter>=2; suppressed by A-kept highs unconditionally
  for (int iter = 0; iter < 100000; ++iter) {
    if (tid == 0) { s_changed = 0; s_undec = 0; }
    __syncthreads();
    for (int i = tid; i < M; i += 1024) {
      unsigned int pos = list[i];
      float s = score[pos];
      if (s > 0.95f) continue;                 // highs: not processed in C
      uint8_t st = state[pos];
      if (!(st & B_KEPT)) continue;            // only B-kept lows
      if (st & C_DEC) continue;
      int y = (int)(pos >> 10), x = (int)(pos & 1023);
      bool sup = false, undec = false;
      for (int dy = -3; dy <= 3 && !sup; ++dy) {
        int ny = y + dy;
        if ((unsigned)ny >= (unsigned)GH) continue;
        int ady = dy < 0 ? -dy : dy;
        int wy = 4 - ady;
        for (int dx = -3; dx <= 3; ++dx) {
          if ((dx | dy) == 0) continue;
          int adx = dx < 0 ? -dx : dx;
          if ((4 - adx) * wy < 2) continue;
          int nx = x + dx;
          if ((unsigned)nx >= (unsigned)GW) continue;
          unsigned int np = (unsigned int)(ny*GW + nx);
          if (!((bitmap[np >> 5] >> (np & 31)) & 1u)) continue;
          float ns = score[np];
          uint8_t nst = state[np];
          if (ns > 0.95f) {
            if (nst & A_KEPT) { sup = true; break; }   // kept high always outranks
          } else {
            if (!(ns > 0.90f && ns < 0.95f)) continue;
            if (!(nst & B_KEPT)) continue;
            if (!(ns > s || (ns == s && np < pos))) continue;
            if (nst & C_KEPT) { sup = true; break; }
            if (!(nst & C_DEC)) undec = true;
          }
        }
      }
      if (sup)            { state[pos] = st | C_DEC;           s_changed = 1; }
      else if (!undec)    { state[pos] = st | C_DEC | C_KEPT;  s_changed = 1; }
      else                s_undec = 1;
    }
    __syncthreads();
    int chg = s_changed, und = s_undec;
    __syncthreads();
    if (!und || !chg) break;
  }
  __syncthreads();

  // ---- Collect final keeps: A-kept highs + C-kept lows
  if (tid == 0) s_k = 0;
  __syncthreads();                                 // bitmap dead; keys alias buf
  for (int i = tid; i < M; i += 1024) {
    unsigned int pos = list[i];
    float s = score[pos];
    uint8_t st = state[pos];
    bool fin = (s > 0.95f) ? ((st & A_KEPT) != 0) : ((st & C_KEPT) != 0);
    if (fin) {
      unsigned int j = atomicAdd(&s_k, 1u);
      if (j < KMAX)
        keys[j] = (((unsigned long long)(0xFFFFFFFFu - __float_as_uint(s))) << 32)
                  | (unsigned long long)pos;       // sort asc = score desc, idx asc
    }
  }
  __syncthreads();
  unsigned int K = min(s_k, (unsigned int)KMAX);
  for (int i = tid; i < KMAX; i += 1024)
    if ((unsigned int)i >= K) keys[i] = ~0ULL;
  __syncthreads();

  // bitonic sort KMAX u64 keys in LDS
  for (unsigned int kk = 2; kk <= KMAX; kk <<= 1) {
    for (unsigned int j = kk >> 1; j > 0; j >>= 1) {
      for (int i = tid; i < KMAX; i += 1024) {
        int ixj = i ^ (int)j;
        if (ixj > i) {
          unsigned long long a = keys[i], b = keys[ixj];
          bool asc = ((i & kk) == 0);
          if (asc ? (a > b) : (a < b)) { keys[i] = b; keys[ixj] = a; }
        }
      }
      __syncthreads();
    }
  }

  int rows = min((int)K, nrows);
  for (int i = tid; i < rows; i += 1024) {
    unsigned long long kv = keys[i];
    unsigned int pos = (unsigned int)(kv & 0xFFFFFFFFu);
    float s = __uint_as_float(0xFFFFFFFFu - (unsigned int)(kv >> 32));
    float fx = (float)(pos & 1023), fy = (float)(pos >> 10);
    out[i*5 + 0] = fx - 2.0f;
    out[i*5 + 1] = fy - 2.0f;
    out[i*5 + 2] = fx + 2.0f;
    out[i*5 + 3] = fy + 2.0f;
    out[i*5 + 4] = s;
  }
}

extern "C" void kernel_launch(void* const* d_in, const int* in_sizes, int n_in,
                              void* d_out, int out_size, void* d_ws, size_t ws_size,
                              hipStream_t stream) {
  const float* x1 = (const float*)d_in[0];
  const float* x2 = (const float*)d_in[1];
  const float* x3 = (const float*)d_in[2];
  char* ws = (char*)d_ws;
  float* rmap  = (float*)ws;                               // 4MB, later reused as score map
  float* Amap  = (float*)(ws + (4u << 20));                // 4MB
  float* Bmap  = (float*)(ws + (8u << 20));                // 4MB
  uint8_t* state = (uint8_t*)(ws + (12u << 20));           // 1MB
  unsigned int* list = (unsigned int*)(ws + (13u << 20));  // 512KB
  unsigned int* mm = (unsigned int*)(ws + (13u << 20) + MAXC*4u);
  float* out = (float*)d_out;

  k_init<<<1, 64, 0, stream>>>(mm);
  k_resid<<<NPIX/4/256, 256, 0, stream>>>((const float4*)x1, (const float4*)x2,
                                          (const float4*)x3, (float4*)rmap, mm);
  dim3 g2(GW/256, GH);
  k_convy<<<g2, 256, 0, stream>>>(rmap, Amap, mm);
  k_convx<<<g2, 256, 0, stream>>>(Amap, Bmap, mm);
  k_cand<<<NPIX/256, 256, 0, stream>>>(Bmap, rmap, state, list, mm);
  k_nms<<<1, 1024, 0, stream>>>(rmap, state, list, mm, out, out_size / 5);
}

// Round 3
// 580.935 us; speedup vs baseline: 1.1294x; 1.1294x over previous
//
#include <hip/hip_runtime.h>
#include <stdint.h>

#define GW 1024
#define GH 1024
#define NPIX (GW*GH)
#define CAP 8192        // max candidates supported (list/sort/adj capacity)
#define ADJ_STRIDE 48   // u16 per adjacency row: [0]=n3|n<<8, [1..n]=outranking nbr ranks

__global__ void k_init(unsigned int* mm) {
  if (threadIdx.x == 0) {
    mm[0] = 0u;            // candidate count
    mm[1] = 0x7F800000u;   // rmin bits (+inf)
    mm[2] = 0u;            // rmax bits
    mm[3] = 0u;            // bmax bits
    mm[4] = 0u;            // nHigh
  }
}

__global__ void k_resid(const float4* __restrict__ x1, const float4* __restrict__ x2,
                        const float4* __restrict__ x3, float4* __restrict__ r,
                        unsigned int* __restrict__ mm) {
  const int N4 = NPIX / 4;
  int t = blockIdx.x * blockDim.x + threadIdx.x;
  float4 s1 = make_float4(0.f,0.f,0.f,0.f);
  float4 s2 = make_float4(0.f,0.f,0.f,0.f);
#pragma unroll
  for (int c = 0; c < 8; ++c) {
    float4 a = x1[c*N4 + t];
    float4 b = x2[c*N4 + t];
    float4 d = x3[c*N4 + t];
    s1.x += fabsf(a.x-b.x); s1.y += fabsf(a.y-b.y);
    s1.z += fabsf(a.z-b.z); s1.w += fabsf(a.w-b.w);
    s2.x += fabsf(b.x-d.x); s2.y += fabsf(b.y-d.y);
    s2.z += fabsf(b.z-d.z); s2.w += fabsf(b.w-d.w);
  }
  float4 rv = make_float4((s1.x+s2.x)*0.5f, (s1.y+s2.y)*0.5f,
                          (s1.z+s2.z)*0.5f, (s1.w+s2.w)*0.5f);
  r[t] = rv;
  float mn = fminf(fminf(rv.x,rv.y), fminf(rv.z,rv.w));
  float mx = fmaxf(fmaxf(rv.x,rv.y), fmaxf(rv.z,rv.w));
#pragma unroll
  for (int o = 32; o > 0; o >>= 1) {
    mn = fminf(mn, __shfl_down(mn, o));
    mx = fmaxf(mx, __shfl_down(mx, o));
  }
  if ((threadIdx.x & 63) == 0) {
    atomicMin(&mm[1], __float_as_uint(mn));
    atomicMax(&mm[2], __float_as_uint(mx));
  }
}

// y-direction ROI-align interp (normalize r inline), exact _interp1d semantics
__global__ void k_convy(const float* __restrict__ r, float* __restrict__ A,
                        const unsigned int* __restrict__ mm) {
  int x = blockIdx.x * 256 + threadIdx.x;
  int y = blockIdx.y;
  float rmin = __uint_as_float(mm[1]);
  float denom = __uint_as_float(mm[2]) - rmin + 1e-6f;
  const float offs[4] = {-1.5f, -0.5f, 0.5f, 1.5f};
  float a = 0.f, b = 0.f;
#pragma unroll
  for (int k = 0; k < 4; ++k) {
    float c = (float)y + offs[k];
    bool valid = (c >= -1.0f) && (c <= (float)GH);
    float cc = fminf(fmaxf(c, 0.0f), (float)(GH - 1));
    int lo = (int)floorf(cc);
    int hi = min(lo + 1, GH - 1);
    float frac = cc - (float)lo;
    float w0 = valid ? 1.0f - frac : 0.0f;
    float w1 = valid ? frac : 0.0f;
    a += ((r[lo*GW + x] - rmin) / denom) * w0;
    b += ((r[hi*GW + x] - rmin) / denom) * w1;
  }
  A[y*GW + x] = a + b;
}

// x-direction interp, /16, and global max of B
__global__ void k_convx(const float* __restrict__ A, float* __restrict__ B,
                        unsigned int* __restrict__ mm) {
  int x = blockIdx.x * 256 + threadIdx.x;
  int y = blockIdx.y;
  const float offs[4] = {-1.5f, -0.5f, 0.5f, 1.5f};
  float a = 0.f, b = 0.f;
#pragma unroll
  for (int k = 0; k < 4; ++k) {
    float c = (float)x + offs[k];
    bool valid = (c >= -1.0f) && (c <= (float)GW);
    float cc = fminf(fmaxf(c, 0.0f), (float)(GW - 1));
    int lo = (int)floorf(cc);
    int hi = min(lo + 1, GW - 1);
    float frac = cc - (float)lo;
    float w0 = valid ? 1.0f - frac : 0.0f;
    float w1 = valid ? frac : 0.0f;
    a += A[y*GW + lo] * w0;
    b += A[y*GW + hi] * w1;
  }
  float v = (a + b) * 0.0625f;   // /16 exact
  B[y*GW + x] = v;
  float mx = v;
#pragma unroll
  for (int o = 32; o > 0; o >>= 1) mx = fmaxf(mx, __shfl_down(mx, o));
  if ((threadIdx.x & 63) == 0) atomicMax(&mm[3], __float_as_uint(mx));
}

// build candidate list, init pos->rank map to invalid
__global__ void k_cand(const float4* __restrict__ B, uint4* __restrict__ map,
                       unsigned int* __restrict__ list, unsigned int* __restrict__ mm) {
  int t = blockIdx.x * 256 + threadIdx.x;
  float bmax = __uint_as_float(mm[3]);
  float dv = bmax + 1e-6f;
  float4 b = B[t];
  map[t] = make_uint4(~0u, ~0u, ~0u, ~0u);
  float l[4] = { b.x/dv, b.y/dv, b.z/dv, b.w/dv };
  unsigned int base = (unsigned int)t * 4u;
#pragma unroll
  for (int k = 0; k < 4; ++k) {
    float s = l[k];
    if (s > 0.90f && !(s == 0.95f)) {
      unsigned int i = atomicAdd(&mm[0], 1u);
      if (i < CAP) list[i] = base + (unsigned int)k;
    }
  }
}

// single block: sort (score desc, pos asc), scatter ranks into map, count highs
__global__ __launch_bounds__(1024) void k_sort(const float* __restrict__ B,
                                               const unsigned int* __restrict__ list,
                                               unsigned int* __restrict__ map,
                                               unsigned int* __restrict__ mm,
                                               unsigned long long* __restrict__ keysOut) {
  __shared__ unsigned long long keys[CAP];
  __shared__ unsigned int s_high;
  const int tid = threadIdx.x;
  if (tid == 0) s_high = 0;
  __syncthreads();
  int M = (int)min(mm[0], (unsigned int)CAP);
  float bmax = __uint_as_float(mm[3]);
  unsigned int hc = 0;
  for (int i = tid; i < CAP; i += 1024) {
    unsigned long long k = ~0ULL;
    if (i < M) {
      unsigned int pos = list[i];
      float s = B[pos] / (bmax + 1e-6f);
      unsigned int sb = __float_as_uint(s);
      k = (((unsigned long long)(0xFFFFFFFFu - sb)) << 32) | (unsigned long long)pos;
      if (s > 0.95f) hc++;
    }
    keys[i] = k;
  }
  atomicAdd(&s_high, hc);
  __syncthreads();
  for (unsigned int kk = 2; kk <= CAP; kk <<= 1) {
    for (unsigned int j = kk >> 1; j > 0; j >>= 1) {
      for (int i = tid; i < CAP; i += 1024) {
        int ixj = i ^ (int)j;
        if (ixj > i) {
          unsigned long long a = keys[i], b = keys[ixj];
          bool asc = ((i & kk) == 0);
          if (asc ? (a > b) : (a < b)) { keys[i] = b; keys[ixj] = a; }
        }
      }
      __syncthreads();
    }
  }
  for (int i = tid; i < CAP; i += 1024) {
    unsigned long long k = keys[i];
    keysOut[i] = k;
    if (i < M) map[(unsigned int)(k & 0xFFFFFFFFu)] = (unsigned int)i;
  }
  if (tid == 0) mm[4] = s_high;
}

// grid-parallel: per rank, list of OUTRANKING conflicting neighbor ranks
// (inter>=3 entries first so stage-B mask is a prefix)
__global__ void k_adj(const unsigned long long* __restrict__ keys,
                      const unsigned int* __restrict__ map,
                      const unsigned int* __restrict__ mm,
                      unsigned short* __restrict__ adj) {
  int r = blockIdx.x * 256 + threadIdx.x;
  int M = (int)min(mm[0], (unsigned int)CAP);
  if (r >= M) return;
  unsigned int pos = (unsigned int)(keys[r] & 0xFFFFFFFFu);
  int y = (int)(pos >> 10), x = (int)(pos & 1023);
  int n = 0, n3 = 0;
  unsigned short* row = adj + (size_t)r * ADJ_STRIDE;
#pragma unroll
  for (int pass = 0; pass < 2; ++pass) {
    for (int dy = -3; dy <= 3; ++dy) {
      int ady = dy < 0 ? -dy : dy;
      int wy = 4 - ady;
      int ny = y + dy;
      if ((unsigned)ny >= (unsigned)GH) continue;
      for (int dx = -3; dx <= 3; ++dx) {
        if ((dx | dy) == 0) continue;
        int adx = dx < 0 ? -dx : dx;
        int prod = (4 - adx) * wy;
        if (prod < 2) continue;
        if ((pass == 0) != (prod >= 3)) continue;
        int nx = x + dx;
        if ((unsigned)nx >= (unsigned)GW) continue;
        unsigned int nrk = map[ny*GW + nx];
        if (nrk < (unsigned int)r) {     // only outranking neighbors matter
          row[1 + n] = (unsigned short)nrk;
          n++;
          if (pass == 0) n3++;
        }
      }
    }
  }
  row[0] = (unsigned short)(n3 | (n << 8));
}

// single block: fixed-point greedy NMS (stages A/B then C) on LDS state,
// then stable compaction in rank order and output write
__global__ __launch_bounds__(1024) void k_nms(const unsigned long long* __restrict__ keys,
                                              const unsigned short* __restrict__ adj,
                                              const unsigned int* __restrict__ mm,
                                              float* __restrict__ out, int nrows) {
  __shared__ unsigned char st[CAP];          // bit0 AB_DEC, bit1 AB_KEPT, bit2 C_DEC, bit3 C_KEPT
  __shared__ unsigned short act[2][CAP];
  __shared__ unsigned int s_cnt[2];
  __shared__ unsigned int scan[1024];
  const int tid = threadIdx.x;
  int M = (int)min(mm[0], (unsigned int)CAP);
  int nH = (int)mm[4];
  for (int i = tid; i < CAP; i += 1024) st[i] = 0;
  for (int i = tid; i < M; i += 1024) act[0][i] = (unsigned short)i;
  if (tid == 0) { s_cnt[0] = (unsigned int)M; s_cnt[1] = 0; }
  __syncthreads();

  // ---- Stages A (highs, all entries) + B (lows, n3 prefix), same fixed point
  int cur = 0;
  for (int round = 0; round < CAP; ++round) {
    unsigned int cnt = s_cnt[cur];
    if (cnt == 0) break;
    for (unsigned int i = tid; i < cnt; i += 1024) {
      int r = act[cur][i];
      bool high = r < nH;
      const unsigned short* row = adj + (size_t)r * ADJ_STRIDE;
      unsigned int hdr = row[0];
      int n = high ? (int)(hdr >> 8) : (int)(hdr & 0xFF);
      bool sup = false, und = false;
      for (int k = 1; k <= n; ++k) {
        int p = row[k];
        if ((p < nH) != high) continue;          // same band only
        unsigned char ps = st[p];
        if (ps & 2) { sup = true; break; }       // kept outranking neighbor
        if (!(ps & 1)) und = true;               // still undecided
      }
      if (sup)          st[r] = 1;
      else if (!und)    st[r] = 3;
      else { unsigned int j = atomicAdd(&s_cnt[cur ^ 1], 1u); act[cur ^ 1][j] = (unsigned short)r; }
    }
    __syncthreads();
    if (tid == 0) s_cnt[cur] = 0;
    cur ^= 1;
    __syncthreads();
  }
  __syncthreads();

  // ---- Stage C: AB-kept lows, thr inter>=2 (all entries); kept highs suppress
  if (tid == 0) { s_cnt[0] = 0; s_cnt[1] = 0; }
  __syncthreads();
  for (int i = nH + tid; i < M; i += 1024)
    if (st[i] & 2) { unsigned int j = atomicAdd(&s_cnt[0], 1u); act[0][j] = (unsigned short)i; }
  __syncthreads();
  cur = 0;
  for (int round = 0; round < CAP; ++round) {
    unsigned int cnt = s_cnt[cur];
    if (cnt == 0) break;
    for (unsigned int i = tid; i < cnt; i += 1024) {
      int r = act[cur][i];
      const unsigned short* row = adj + (size_t)r * ADJ_STRIDE;
      unsigned int hdr = row[0];
      int n = (int)(hdr >> 8);
      bool sup = false, und = false;
      for (int k = 1; k <= n; ++k) {
        int p = row[k];
        unsigned char ps = st[p];
        if (p < nH) {
          if (ps & 2) { sup = true; break; }     // A-kept high always wins
        } else {
          if (!(ps & 2)) continue;               // not in C candidate set
          if (ps & 8) { sup = true; break; }     // C-kept outranking low
          if (!(ps & 4)) und = true;
        }
      }
      if (sup)          st[r] |= 4;
      else if (!und)    st[r] |= 12;
      else { unsigned int j = atomicAdd(&s_cnt[cur ^ 1], 1u); act[cur ^ 1][j] = (unsigned short)r; }
    }
    __syncthreads();
    if (tid == 0) s_cnt[cur] = 0;
    cur ^= 1;
    __syncthreads();
  }
  __syncthreads();

  // ---- stable compaction by rank + output
  int base = tid * 8;
  int cnt = 0;
  unsigned int flags = 0;
#pragma unroll
  for (int k = 0; k < 8; ++k) {
    int r = base + k;
    bool keep = false;
    if (r < M) keep = (r < nH) ? ((st[r] & 2) != 0) : ((st[r] & 8) != 0);
    if (keep) { flags |= 1u << k; cnt++; }
  }
  scan[tid] = (unsigned int)cnt;
  __syncthreads();
  for (int off = 1; off < 1024; off <<= 1) {
    unsigned int v = scan[tid];
    unsigned int a = (tid >= off) ? scan[tid - off] : 0u;
    __syncthreads();
    scan[tid] = v + a;
    __syncthreads();
  }
  unsigned int off0 = scan[tid] - (unsigned int)cnt;   // exclusive prefix
  int w = 0;
#pragma unroll
  for (int k = 0; k < 8; ++k) {
    if (flags & (1u << k)) {
      int r = base + k;
      unsigned int j = off0 + (unsigned int)w; w++;
      if ((int)j < nrows) {
        unsigned long long kv = keys[r];
        unsigned int pos = (unsigned int)(kv & 0xFFFFFFFFu);
        float s = __uint_as_float(0xFFFFFFFFu - (unsigned int)(kv >> 32));
        float fx = (float)(pos & 1023), fy = (float)(pos >> 10);
        out[j*5 + 0] = fx - 2.0f;
        out[j*5 + 1] = fy - 2.0f;
        out[j*5 + 2] = fx + 2.0f;
        out[j*5 + 3] = fy + 2.0f;
        out[j*5 + 4] = s;
      }
    }
  }
}

extern "C" void kernel_launch(void* const* d_in, const int* in_sizes, int n_in,
                              void* d_out, int out_size, void* d_ws, size_t ws_size,
                              hipStream_t stream) {
  const float* x1 = (const float*)d_in[0];
  const float* x2 = (const float*)d_in[1];
  const float* x3 = (const float*)d_in[2];
  char* ws = (char*)d_ws;
  float* rmap = (float*)ws;                                  // 4MB
  float* Amap = (float*)(ws + (4u << 20));                   // 4MB (reused as map after convx)
  float* Bmap = (float*)(ws + (8u << 20));                   // 4MB
  unsigned int* map = (unsigned int*)(ws + (4u << 20));      // overlays Amap (dead after convx)
  unsigned int* mm  = (unsigned int*)(ws + (12u << 20));
  unsigned int* list = (unsigned int*)(ws + (12u << 20) + 4096u);
  unsigned long long* keys = (unsigned long long*)(ws + (12u << 20) + (64u << 10));
  unsigned short* adj = (unsigned short*)(ws + (12u << 20) + (128u << 10));  // 768KB
  float* out = (float*)d_out;

  k_init<<<1, 64, 0, stream>>>(mm);
  k_resid<<<NPIX/4/256, 256, 0, stream>>>((const float4*)x1, (const float4*)x2,
                                          (const float4*)x3, (float4*)rmap, mm);
  dim3 g2(GW/256, GH);
  k_convy<<<g2, 256, 0, stream>>>(rmap, Amap, mm);
  k_convx<<<g2, 256, 0, stream>>>(Amap, Bmap, mm);
  k_cand<<<NPIX/4/256, 256, 0, stream>>>((const float4*)Bmap, (uint4*)map, list, mm);
  k_sort<<<1, 1024, 0, stream>>>(Bmap, list, map, mm, keys);
  k_adj<<<CAP/256, 256, 0, stream>>>(keys, map, mm, adj);
  k_nms<<<1, 1024, 0, stream>>>(keys, adj, mm, out, out_size / 5);
}

// Round 4
// 216.825 us; speedup vs baseline: 3.0261x; 2.6793x over previous
//
#include <hip/hip_runtime.h>
#include <stdint.h>

#define GW 1024
#define GH 1024
#define NPIX (GW*GH)
#define CAP 8192        // max candidates supported (list/sort/adj capacity)
#define ADJ_STRIDE 48   // u16 per adjacency row: [0]=n3|n<<8, [1..n]=outranking nbr ranks

// residual map + per-block min/max partials (no global atomics)
__global__ void k_resid(const float4* __restrict__ x1, const float4* __restrict__ x2,
                        const float4* __restrict__ x3, float4* __restrict__ r,
                        float2* __restrict__ pmm) {
  const int N4 = NPIX / 4;
  int t = blockIdx.x * blockDim.x + threadIdx.x;
  float4 s1 = make_float4(0.f,0.f,0.f,0.f);
  float4 s2 = make_float4(0.f,0.f,0.f,0.f);
#pragma unroll
  for (int c = 0; c < 8; ++c) {
    float4 a = x1[c*N4 + t];
    float4 b = x2[c*N4 + t];
    float4 d = x3[c*N4 + t];
    s1.x += fabsf(a.x-b.x); s1.y += fabsf(a.y-b.y);
    s1.z += fabsf(a.z-b.z); s1.w += fabsf(a.w-b.w);
    s2.x += fabsf(b.x-d.x); s2.y += fabsf(b.y-d.y);
    s2.z += fabsf(b.z-d.z); s2.w += fabsf(b.w-d.w);
  }
  float4 rv = make_float4((s1.x+s2.x)*0.5f, (s1.y+s2.y)*0.5f,
                          (s1.z+s2.z)*0.5f, (s1.w+s2.w)*0.5f);
  r[t] = rv;
  float mn = fminf(fminf(rv.x,rv.y), fminf(rv.z,rv.w));
  float mx = fmaxf(fmaxf(rv.x,rv.y), fmaxf(rv.z,rv.w));
#pragma unroll
  for (int o = 32; o > 0; o >>= 1) {
    mn = fminf(mn, __shfl_down(mn, o));
    mx = fmaxf(mx, __shfl_down(mx, o));
  }
  __shared__ float smn[4], smx[4];
  int wid = threadIdx.x >> 6;
  if ((threadIdx.x & 63) == 0) { smn[wid] = mn; smx[wid] = mx; }
  __syncthreads();
  if (threadIdx.x == 0) {
    float a = fminf(fminf(smn[0], smn[1]), fminf(smn[2], smn[3]));
    float b = fmaxf(fmaxf(smx[0], smx[1]), fmaxf(smx[2], smx[3]));
    pmm[blockIdx.x] = make_float2(a, b);
  }
}

// 1 block: reduce 1024 block partials -> rmin/rmax
__global__ __launch_bounds__(1024) void k_reduce1(const float2* __restrict__ pmm,
                                                  unsigned int* __restrict__ mm) {
  int t = threadIdx.x;
  float2 p = pmm[t];
  float mn = p.x, mx = p.y;
#pragma unroll
  for (int o = 32; o > 0; o >>= 1) {
    mn = fminf(mn, __shfl_down(mn, o));
    mx = fmaxf(mx, __shfl_down(mx, o));
  }
  __shared__ float smn[16], smx[16];
  int wid = t >> 6;
  if ((t & 63) == 0) { smn[wid] = mn; smx[wid] = mx; }
  __syncthreads();
  if (t == 0) {
    mn = smn[0]; mx = smx[0];
#pragma unroll
    for (int i = 1; i < 16; ++i) { mn = fminf(mn, smn[i]); mx = fmaxf(mx, smx[i]); }
    mm[1] = __float_as_uint(mn);
    mm[2] = __float_as_uint(mx);
  }
}

// y-direction ROI-align interp (normalize r inline), exact _interp1d semantics
__global__ void k_convy(const float* __restrict__ r, float* __restrict__ A,
                        const unsigned int* __restrict__ mm) {
  int x = blockIdx.x * 256 + threadIdx.x;
  int y = blockIdx.y;
  float rmin = __uint_as_float(mm[1]);
  float denom = __uint_as_float(mm[2]) - rmin + 1e-6f;
  const float offs[4] = {-1.5f, -0.5f, 0.5f, 1.5f};
  float a = 0.f, b = 0.f;
#pragma unroll
  for (int k = 0; k < 4; ++k) {
    float c = (float)y + offs[k];
    bool valid = (c >= -1.0f) && (c <= (float)GH);
    float cc = fminf(fmaxf(c, 0.0f), (float)(GH - 1));
    int lo = (int)floorf(cc);
    int hi = min(lo + 1, GH - 1);
    float frac = cc - (float)lo;
    float w0 = valid ? 1.0f - frac : 0.0f;
    float w1 = valid ? frac : 0.0f;
    a += ((r[lo*GW + x] - rmin) / denom) * w0;
    b += ((r[hi*GW + x] - rmin) / denom) * w1;
  }
  A[y*GW + x] = a + b;
}

// x-direction interp, /16; one block per row, row staged in LDS; block max partial
__global__ void k_convx(const float* __restrict__ A, float* __restrict__ B,
                        float* __restrict__ pbmax) {
  __shared__ float sA[GW];
  __shared__ float smx[4];
  int y = blockIdx.x, t = threadIdx.x;
  ((float4*)sA)[t] = ((const float4*)(A + (size_t)y*GW))[t];
  __syncthreads();
  const float offs[4] = {-1.5f, -0.5f, 0.5f, 1.5f};
  float mxv = 0.0f;   // B >= 0 always (weights>=0, normalized r>=0)
#pragma unroll
  for (int q = 0; q < 4; ++q) {
    int x = t + 256*q;
    float a = 0.f, b = 0.f;
#pragma unroll
    for (int k = 0; k < 4; ++k) {
      float c = (float)x + offs[k];
      bool valid = (c >= -1.0f) && (c <= (float)GW);
      float cc = fminf(fmaxf(c, 0.0f), (float)(GW - 1));
      int lo = (int)floorf(cc);
      int hi = min(lo + 1, GW - 1);
      float frac = cc - (float)lo;
      float w0 = valid ? 1.0f - frac : 0.0f;
      float w1 = valid ? frac : 0.0f;
      a += sA[lo] * w0;
      b += sA[hi] * w1;
    }
    float v = (a + b) * 0.0625f;   // /16 exact
    B[(size_t)y*GW + x] = v;
    mxv = fmaxf(mxv, v);
  }
#pragma unroll
  for (int o = 32; o > 0; o >>= 1) mxv = fmaxf(mxv, __shfl_down(mxv, o));
  int wid = t >> 6;
  if ((t & 63) == 0) smx[wid] = mxv;
  __syncthreads();
  if (t == 0)
    pbmax[y] = fmaxf(fmaxf(smx[0], smx[1]), fmaxf(smx[2], smx[3]));
}

// 1 block: reduce 1024 row maxima -> bmax; also zero candidate counter
__global__ __launch_bounds__(1024) void k_reduce2(const float* __restrict__ pbmax,
                                                  unsigned int* __restrict__ mm) {
  int t = threadIdx.x;
  float mx = pbmax[t];
#pragma unroll
  for (int o = 32; o > 0; o >>= 1) mx = fmaxf(mx, __shfl_down(mx, o));
  __shared__ float smx[16];
  int wid = t >> 6;
  if ((t & 63) == 0) smx[wid] = mx;
  __syncthreads();
  if (t == 0) {
    mx = smx[0];
#pragma unroll
    for (int i = 1; i < 16; ++i) mx = fmaxf(mx, smx[i]);
    mm[3] = __float_as_uint(mx);
    mm[0] = 0u;   // candidate count
    mm[4] = 0u;   // nHigh (k_sort overwrites)
  }
}

// candidate list via block-aggregated compaction (<=1 atomic per block);
// init pos->rank map to invalid
__global__ void k_cand(const float4* __restrict__ B, uint4* __restrict__ map,
                       unsigned int* __restrict__ list, unsigned int* __restrict__ mm) {
  int t = blockIdx.x * 256 + threadIdx.x;
  int tid = threadIdx.x;
  float bmax = __uint_as_float(mm[3]);
  float dv = bmax + 1e-6f;
  float4 b = B[t];
  map[t] = make_uint4(~0u, ~0u, ~0u, ~0u);
  float l[4] = { b.x/dv, b.y/dv, b.z/dv, b.w/dv };
  unsigned int flags = 0; int cnt = 0;
#pragma unroll
  for (int k = 0; k < 4; ++k) {
    float s = l[k];
    if (s > 0.90f && !(s == 0.95f)) { flags |= 1u << k; cnt++; }
  }
  __shared__ unsigned int sscan[256];
  __shared__ unsigned int sbase;
  sscan[tid] = (unsigned int)cnt;
  __syncthreads();
  for (int off = 1; off < 256; off <<= 1) {
    unsigned int v = sscan[tid];
    unsigned int a = (tid >= off) ? sscan[tid - off] : 0u;
    __syncthreads();
    sscan[tid] = v + a;
    __syncthreads();
  }
  if (tid == 255) {
    unsigned int tot = sscan[255];
    if (tot) sbase = atomicAdd(&mm[0], tot);
  }
  __syncthreads();
  if (flags) {
    unsigned int o = sbase + sscan[tid] - (unsigned int)cnt;
    unsigned int base4 = (unsigned int)t * 4u;
#pragma unroll
    for (int k = 0; k < 4; ++k) {
      if ((flags >> k) & 1u) {
        if (o < CAP) list[o] = base4 + (unsigned int)k;
        o++;
      }
    }
  }
}

// single block: sort (score desc, pos asc) over P=next_pow2(M), scatter ranks,
// count highs
__global__ __launch_bounds__(1024) void k_sort(const float* __restrict__ B,
                                               const unsigned int* __restrict__ list,
                                               unsigned int* __restrict__ map,
                                               unsigned int* __restrict__ mm,
                                               unsigned long long* __restrict__ keysOut) {
  __shared__ unsigned long long keys[CAP];
  __shared__ unsigned int s_high;
  const int tid = threadIdx.x;
  if (tid == 0) s_high = 0;
  __syncthreads();
  int M = (int)min(mm[0], (unsigned int)CAP);
  unsigned int P = 2;
  while (P < (unsigned int)M) P <<= 1;
  float bmax = __uint_as_float(mm[3]);
  unsigned int hc = 0;
  for (unsigned int i = tid; i < P; i += 1024) {
    unsigned long long k = ~0ULL;
    if ((int)i < M) {
      unsigned int pos = list[i];
      float s = B[pos] / (bmax + 1e-6f);
      unsigned int sb = __float_as_uint(s);
      k = (((unsigned long long)(0xFFFFFFFFu - sb)) << 32) | (unsigned long long)pos;
      if (s > 0.95f) hc++;
    }
    keys[i] = k;
  }
  if (hc) atomicAdd(&s_high, hc);
  __syncthreads();
  for (unsigned int kk = 2; kk <= P; kk <<= 1) {
    for (unsigned int j = kk >> 1; j > 0; j >>= 1) {
      for (unsigned int i = tid; i < P; i += 1024) {
        unsigned int ixj = i ^ j;
        if (ixj > i) {
          unsigned long long a = keys[i], b = keys[ixj];
          bool asc = ((i & kk) == 0);
          if (asc ? (a > b) : (a < b)) { keys[i] = b; keys[ixj] = a; }
        }
      }
      __syncthreads();
    }
  }
  for (unsigned int i = tid; i < P; i += 1024) {
    unsigned long long k = keys[i];
    keysOut[i] = k;
    if ((int)i < M) map[(unsigned int)(k & 0xFFFFFFFFu)] = i;
  }
  if (tid == 0) mm[4] = s_high;
}

// grid-parallel: per rank, list of OUTRANKING conflicting neighbor ranks
// (inter>=3 entries first so stage-B mask is a prefix)
__global__ void k_adj(const unsigned long long* __restrict__ keys,
                      const unsigned int* __restrict__ map,
                      const unsigned int* __restrict__ mm,
                      unsigned short* __restrict__ adj) {
  int r = blockIdx.x * 256 + threadIdx.x;
  int M = (int)min(mm[0], (unsigned int)CAP);
  if (r >= M) return;
  unsigned int pos = (unsigned int)(keys[r] & 0xFFFFFFFFu);
  int y = (int)(pos >> 10), x = (int)(pos & 1023);
  int n = 0, n3 = 0;
  unsigned short* row = adj + (size_t)r * ADJ_STRIDE;
#pragma unroll
  for (int pass = 0; pass < 2; ++pass) {
    for (int dy = -3; dy <= 3; ++dy) {
      int ady = dy < 0 ? -dy : dy;
      int wy = 4 - ady;
      int ny = y + dy;
      if ((unsigned)ny >= (unsigned)GH) continue;
      for (int dx = -3; dx <= 3; ++dx) {
        if ((dx | dy) == 0) continue;
        int adx = dx < 0 ? -dx : dx;
        int prod = (4 - adx) * wy;
        if (prod < 2) continue;
        if ((pass == 0) != (prod >= 3)) continue;
        int nx = x + dx;
        if ((unsigned)nx >= (unsigned)GW) continue;
        unsigned int nrk = map[ny*GW + nx];
        if (nrk < (unsigned int)r) {     // only outranking neighbors matter
          row[1 + n] = (unsigned short)nrk;
          n++;
          if (pass == 0) n3++;
        }
      }
    }
  }
  row[0] = (unsigned short)(n3 | (n << 8));
}

// single block: fixed-point greedy NMS (stages A/B then C) on LDS state,
// then stable compaction in rank order and output write
__global__ __launch_bounds__(1024) void k_nms(const unsigned long long* __restrict__ keys,
                                              const unsigned short* __restrict__ adj,
                                              const unsigned int* __restrict__ mm,
                                              float* __restrict__ out, int nrows) {
  __shared__ unsigned char st[CAP];          // bit0 AB_DEC, bit1 AB_KEPT, bit2 C_DEC, bit3 C_KEPT
  __shared__ unsigned short act[2][CAP];
  __shared__ unsigned int s_cnt[2];
  __shared__ unsigned int scan[1024];
  const int tid = threadIdx.x;
  int M = (int)min(mm[0], (unsigned int)CAP);
  int nH = (int)mm[4];
  for (int i = tid; i < CAP; i += 1024) st[i] = 0;
  for (int i = tid; i < M; i += 1024) act[0][i] = (unsigned short)i;
  if (tid == 0) { s_cnt[0] = (unsigned int)M; s_cnt[1] = 0; }
  __syncthreads();

  // ---- Stages A (highs, all entries) + B (lows, n3 prefix), same fixed point
  int cur = 0;
  for (int round = 0; round < CAP; ++round) {
    unsigned int cnt = s_cnt[cur];
    if (cnt == 0) break;
    for (unsigned int i = tid; i < cnt; i += 1024) {
      int r = act[cur][i];
      bool high = r < nH;
      const unsigned short* row = adj + (size_t)r * ADJ_STRIDE;
      unsigned int hdr = row[0];
      int n = high ? (int)(hdr >> 8) : (int)(hdr & 0xFF);
      bool sup = false, und = false;
      for (int k = 1; k <= n; ++k) {
        int p = row[k];
        if ((p < nH) != high) continue;          // same band only
        unsigned char ps = st[p];
        if (ps & 2) { sup = true; break; }       // kept outranking neighbor
        if (!(ps & 1)) und = true;               // still undecided
      }
      if (sup)          st[r] = 1;
      else if (!und)    st[r] = 3;
      else { unsigned int j = atomicAdd(&s_cnt[cur ^ 1], 1u); act[cur ^ 1][j] = (unsigned short)r; }
    }
    __syncthreads();
    if (tid == 0) s_cnt[cur] = 0;
    cur ^= 1;
    __syncthreads();
  }
  __syncthreads();

  // ---- Stage C: AB-kept lows, thr inter>=2 (all entries); kept highs suppress
  if (tid == 0) { s_cnt[0] = 0; s_cnt[1] = 0; }
  __syncthreads();
  for (int i = nH + tid; i < M; i += 1024)
    if (st[i] & 2) { unsigned int j = atomicAdd(&s_cnt[0], 1u); act[0][j] = (unsigned short)i; }
  __syncthreads();
  cur = 0;
  for (int round = 0; round < CAP; ++round) {
    unsigned int cnt = s_cnt[cur];
    if (cnt == 0) break;
    for (unsigned int i = tid; i < cnt; i += 1024) {
      int r = act[cur][i];
      const unsigned short* row = adj + (size_t)r * ADJ_STRIDE;
      unsigned int hdr = row[0];
      int n = (int)(hdr >> 8);
      bool sup = false, und = false;
      for (int k = 1; k <= n; ++k) {
        int p = row[k];
        unsigned char ps = st[p];
        if (p < nH) {
          if (ps & 2) { sup = true; break; }     // A-kept high always wins
        } else {
          if (!(ps & 2)) continue;               // not in C candidate set
          if (ps & 8) { sup = true; break; }     // C-kept outranking low
          if (!(ps & 4)) und = true;
        }
      }
      if (sup)          st[r] |= 4;
      else if (!und)    st[r] |= 12;
      else { unsigned int j = atomicAdd(&s_cnt[cur ^ 1], 1u); act[cur ^ 1][j] = (unsigned short)r; }
    }
    __syncthreads();
    if (tid == 0) s_cnt[cur] = 0;
    cur ^= 1;
    __syncthreads();
  }
  __syncthreads();

  // ---- stable compaction by rank + output
  int base = tid * 8;
  int cnt = 0;
  unsigned int flags = 0;
#pragma unroll
  for (int k = 0; k < 8; ++k) {
    int r = base + k;
    bool keep = false;
    if (r < M) keep = (r < nH) ? ((st[r] & 2) != 0) : ((st[r] & 8) != 0);
    if (keep) { flags |= 1u << k; cnt++; }
  }
  scan[tid] = (unsigned int)cnt;
  __syncthreads();
  for (int off = 1; off < 1024; off <<= 1) {
    unsigned int v = scan[tid];
    unsigned int a = (tid >= off) ? scan[tid - off] : 0u;
    __syncthreads();
    scan[tid] = v + a;
    __syncthreads();
  }
  unsigned int off0 = scan[tid] - (unsigned int)cnt;   // exclusive prefix
  int w = 0;
#pragma unroll
  for (int k = 0; k < 8; ++k) {
    if (flags & (1u << k)) {
      int r = base + k;
      unsigned int j = off0 + (unsigned int)w; w++;
      if ((int)j < nrows) {
        unsigned long long kv = keys[r];
        unsigned int pos = (unsigned int)(kv & 0xFFFFFFFFu);
        float s = __uint_as_float(0xFFFFFFFFu - (unsigned int)(kv >> 32));
        float fx = (float)(pos & 1023), fy = (float)(pos >> 10);
        out[j*5 + 0] = fx - 2.0f;
        out[j*5 + 1] = fy - 2.0f;
        out[j*5 + 2] = fx + 2.0f;
        out[j*5 + 3] = fy + 2.0f;
        out[j*5 + 4] = s;
      }
    }
  }
}

extern "C" void kernel_launch(void* const* d_in, const int* in_sizes, int n_in,
                              void* d_out, int out_size, void* d_ws, size_t ws_size,
                              hipStream_t stream) {
  const float* x1 = (const float*)d_in[0];
  const float* x2 = (const float*)d_in[1];
  const float* x3 = (const float*)d_in[2];
  char* ws = (char*)d_ws;
  float* rmap = (float*)ws;                                  // 4MB
  float* Amap = (float*)(ws + (4u << 20));                   // 4MB (reused as map)
  float* Bmap = (float*)(ws + (8u << 20));                   // 4MB
  unsigned int* map = (unsigned int*)(ws + (4u << 20));      // overlays Amap (dead after convx)
  unsigned int* mm  = (unsigned int*)(ws + (12u << 20));
  unsigned int* list = (unsigned int*)(ws + (12u << 20) + 4096u);
  unsigned long long* keys = (unsigned long long*)(ws + (12u << 20) + (64u << 10));
  unsigned short* adj = (unsigned short*)(ws + (12u << 20) + (128u << 10));  // 768KB
  float2* pmm = (float2*)(ws + (13u << 20));                 // 8KB
  float* pbmax = (float*)(ws + (13u << 20) + (16u << 10));   // 4KB
  float* out = (float*)d_out;

  k_resid<<<NPIX/4/256, 256, 0, stream>>>((const float4*)x1, (const float4*)x2,
                                          (const float4*)x3, (float4*)rmap, pmm);
  k_reduce1<<<1, 1024, 0, stream>>>(pmm, mm);
  dim3 g2(GW/256, GH);
  k_convy<<<g2, 256, 0, stream>>>(rmap, Amap, mm);
  k_convx<<<GH, 256, 0, stream>>>(Amap, Bmap, pbmax);
  k_reduce2<<<1, 1024, 0, stream>>>(pbmax, mm);
  k_cand<<<NPIX/4/256, 256, 0, stream>>>((const float4*)Bmap, (uint4*)map, list, mm);
  k_sort<<<1, 1024, 0, stream>>>(Bmap, list, map, mm, keys);
  k_adj<<<CAP/256, 256, 0, stream>>>(keys, map, mm, adj);
  k_nms<<<1, 1024, 0, stream>>>(keys, adj, mm, out, out_size / 5);
}

// Round 5
// 199.379 us; speedup vs baseline: 3.2908x; 1.0875x over previous
//
#include <hip/hip_runtime.h>
#include <stdint.h>

#define GW 1024
#define GH 1024
#define NPIX (GW*GH)
#define CAP 8192        // max candidates (list/adj capacity)
#define KCAP 4096       // max final keeps held for output ordering
#define ADJ_STRIDE 48   // u16: [0]=n3|n<<6|high<<12, [1..n]= nid | nbrHigh<<15

// residual map + per-block min/max partials (no global atomics)
__global__ void k_resid(const float4* __restrict__ x1, const float4* __restrict__ x2,
                        const float4* __restrict__ x3, float4* __restrict__ r,
                        float2* __restrict__ pmm) {
  const int N4 = NPIX / 4;
  int t = blockIdx.x * blockDim.x + threadIdx.x;
  float4 s1 = make_float4(0.f,0.f,0.f,0.f);
  float4 s2 = make_float4(0.f,0.f,0.f,0.f);
#pragma unroll
  for (int c = 0; c < 8; ++c) {
    float4 a = x1[c*N4 + t];
    float4 b = x2[c*N4 + t];
    float4 d = x3[c*N4 + t];
    s1.x += fabsf(a.x-b.x); s1.y += fabsf(a.y-b.y);
    s1.z += fabsf(a.z-b.z); s1.w += fabsf(a.w-b.w);
    s2.x += fabsf(b.x-d.x); s2.y += fabsf(b.y-d.y);
    s2.z += fabsf(b.z-d.z); s2.w += fabsf(b.w-d.w);
  }
  float4 rv = make_float4((s1.x+s2.x)*0.5f, (s1.y+s2.y)*0.5f,
                          (s1.z+s2.z)*0.5f, (s1.w+s2.w)*0.5f);
  r[t] = rv;
  float mn = fminf(fminf(rv.x,rv.y), fminf(rv.z,rv.w));
  float mx = fmaxf(fmaxf(rv.x,rv.y), fmaxf(rv.z,rv.w));
#pragma unroll
  for (int o = 32; o > 0; o >>= 1) {
    mn = fminf(mn, __shfl_down(mn, o));
    mx = fmaxf(mx, __shfl_down(mx, o));
  }
  __shared__ float smn[4], smx[4];
  int wid = threadIdx.x >> 6;
  if ((threadIdx.x & 63) == 0) { smn[wid] = mn; smx[wid] = mx; }
  __syncthreads();
  if (threadIdx.x == 0) {
    float a = fminf(fminf(smn[0], smn[1]), fminf(smn[2], smn[3]));
    float b = fmaxf(fmaxf(smx[0], smx[1]), fmaxf(smx[2], smx[3]));
    pmm[blockIdx.x] = make_float2(a, b);
  }
}

// 1 block: reduce 1024 block partials -> rmin/rmax
__global__ __launch_bounds__(1024) void k_reduce1(const float2* __restrict__ pmm,
                                                  unsigned int* __restrict__ mm) {
  int t = threadIdx.x;
  float2 p = pmm[t];
  float mn = p.x, mx = p.y;
#pragma unroll
  for (int o = 32; o > 0; o >>= 1) {
    mn = fminf(mn, __shfl_down(mn, o));
    mx = fmaxf(mx, __shfl_down(mx, o));
  }
  __shared__ float smn[16], smx[16];
  int wid = t >> 6;
  if ((t & 63) == 0) { smn[wid] = mn; smx[wid] = mx; }
  __syncthreads();
  if (t == 0) {
    mn = smn[0]; mx = smx[0];
#pragma unroll
    for (int i = 1; i < 16; ++i) { mn = fminf(mn, smn[i]); mx = fmaxf(mx, smx[i]); }
    mm[1] = __float_as_uint(mn);
    mm[2] = __float_as_uint(mx);
  }
}

// y-direction ROI-align interp (normalize r inline), exact _interp1d semantics
__global__ void k_convy(const float* __restrict__ r, float* __restrict__ A,
                        const unsigned int* __restrict__ mm) {
  int x = blockIdx.x * 256 + threadIdx.x;
  int y = blockIdx.y;
  float rmin = __uint_as_float(mm[1]);
  float denom = __uint_as_float(mm[2]) - rmin + 1e-6f;
  const float offs[4] = {-1.5f, -0.5f, 0.5f, 1.5f};
  float a = 0.f, b = 0.f;
#pragma unroll
  for (int k = 0; k < 4; ++k) {
    float c = (float)y + offs[k];
    bool valid = (c >= -1.0f) && (c <= (float)GH);
    float cc = fminf(fmaxf(c, 0.0f), (float)(GH - 1));
    int lo = (int)floorf(cc);
    int hi = min(lo + 1, GH - 1);
    float frac = cc - (float)lo;
    float w0 = valid ? 1.0f - frac : 0.0f;
    float w1 = valid ? frac : 0.0f;
    a += ((r[lo*GW + x] - rmin) / denom) * w0;
    b += ((r[hi*GW + x] - rmin) / denom) * w1;
  }
  A[y*GW + x] = a + b;
}

// x-direction interp, /16; one block per row, row staged in LDS; block max partial
__global__ void k_convx(const float* __restrict__ A, float* __restrict__ B,
                        float* __restrict__ pbmax) {
  __shared__ float sA[GW];
  __shared__ float smx[4];
  int y = blockIdx.x, t = threadIdx.x;
  ((float4*)sA)[t] = ((const float4*)(A + (size_t)y*GW))[t];
  __syncthreads();
  const float offs[4] = {-1.5f, -0.5f, 0.5f, 1.5f};
  float mxv = 0.0f;   // B >= 0 always (weights>=0, normalized r>=0)
#pragma unroll
  for (int q = 0; q < 4; ++q) {
    int x = t + 256*q;
    float a = 0.f, b = 0.f;
#pragma unroll
    for (int k = 0; k < 4; ++k) {
      float c = (float)x + offs[k];
      bool valid = (c >= -1.0f) && (c <= (float)GW);
      float cc = fminf(fmaxf(c, 0.0f), (float)(GW - 1));
      int lo = (int)floorf(cc);
      int hi = min(lo + 1, GW - 1);
      float frac = cc - (float)lo;
      float w0 = valid ? 1.0f - frac : 0.0f;
      float w1 = valid ? frac : 0.0f;
      a += sA[lo] * w0;
      b += sA[hi] * w1;
    }
    float v = (a + b) * 0.0625f;   // /16 exact
    B[(size_t)y*GW + x] = v;
    mxv = fmaxf(mxv, v);
  }
#pragma unroll
  for (int o = 32; o > 0; o >>= 1) mxv = fmaxf(mxv, __shfl_down(mxv, o));
  int wid = t >> 6;
  if ((t & 63) == 0) smx[wid] = mxv;
  __syncthreads();
  if (t == 0)
    pbmax[y] = fmaxf(fmaxf(smx[0], smx[1]), fmaxf(smx[2], smx[3]));
}

// 1 block: reduce 1024 row maxima -> bmax; also zero candidate counter
__global__ __launch_bounds__(1024) void k_reduce2(const float* __restrict__ pbmax,
                                                  unsigned int* __restrict__ mm) {
  int t = threadIdx.x;
  float mx = pbmax[t];
#pragma unroll
  for (int o = 32; o > 0; o >>= 1) mx = fmaxf(mx, __shfl_down(mx, o));
  __shared__ float smx[16];
  int wid = t >> 6;
  if ((t & 63) == 0) smx[wid] = mx;
  __syncthreads();
  if (t == 0) {
    mx = smx[0];
#pragma unroll
    for (int i = 1; i < 16; ++i) mx = fmaxf(mx, smx[i]);
    mm[3] = __float_as_uint(mx);
    mm[0] = 0u;   // candidate count
  }
}

// candidate compaction (<=1 atomic per block); ids in arbitrary order.
// writes list[id]=pos, scores[id]=s, map[pos]=id (else ~0)
__global__ void k_cand(const float4* __restrict__ B, uint4* __restrict__ map,
                       unsigned int* __restrict__ list, float* __restrict__ scores,
                       unsigned int* __restrict__ mm) {
  int t = blockIdx.x * 256 + threadIdx.x;
  int tid = threadIdx.x;
  float bmax = __uint_as_float(mm[3]);
  float dv = bmax + 1e-6f;
  float4 b = B[t];
  float l[4] = { b.x/dv, b.y/dv, b.z/dv, b.w/dv };
  unsigned int flags = 0; int cnt = 0;
#pragma unroll
  for (int k = 0; k < 4; ++k) {
    float s = l[k];
    if (s > 0.90f && !(s == 0.95f)) { flags |= 1u << k; cnt++; }
  }
  __shared__ unsigned int sscan[256];
  __shared__ unsigned int sbase;
  sscan[tid] = (unsigned int)cnt;
  __syncthreads();
  for (int off = 1; off < 256; off <<= 1) {
    unsigned int v = sscan[tid];
    unsigned int a = (tid >= off) ? sscan[tid - off] : 0u;
    __syncthreads();
    sscan[tid] = v + a;
    __syncthreads();
  }
  if (tid == 255) {
    unsigned int tot = sscan[255];
    if (tot) sbase = atomicAdd(&mm[0], tot);
  }
  __syncthreads();
  unsigned int mv[4] = { ~0u, ~0u, ~0u, ~0u };
  if (flags) {
    unsigned int o = sbase + sscan[tid] - (unsigned int)cnt;
    unsigned int base4 = (unsigned int)t * 4u;
#pragma unroll
    for (int k = 0; k < 4; ++k) {
      if ((flags >> k) & 1u) {
        if (o < CAP) { list[o] = base4 + (unsigned int)k; scores[o] = l[k]; mv[k] = o; }
        o++;
      }
    }
  }
  map[t] = make_uint4(mv[0], mv[1], mv[2], mv[3]);
}

// grid-parallel: per id, list of OUTRANKING conflicting neighbor ids
// (inter>=3 entries first so stage-B mask is a prefix).
// priority: score desc, pos asc. scores>=0 so float order == uint-bit order.
__global__ void k_adj(const unsigned int* __restrict__ list,
                      const float* __restrict__ scores,
                      const unsigned int* __restrict__ map,
                      const unsigned int* __restrict__ mm,
                      unsigned short* __restrict__ adj) {
  int r = blockIdx.x * 256 + threadIdx.x;
  int M = (int)min(mm[0], (unsigned int)CAP);
  if (r >= M) return;
  unsigned int pos = list[r];
  float s = scores[r];
  unsigned int sb = __float_as_uint(s);
  unsigned int high = (s > 0.95f) ? 1u : 0u;
  int y = (int)(pos >> 10), x = (int)(pos & 1023);
  int n = 0, n3 = 0;
  unsigned short* row = adj + (size_t)r * ADJ_STRIDE;
#pragma unroll
  for (int pass = 0; pass < 2; ++pass) {
    for (int dy = -3; dy <= 3; ++dy) {
      int ady = dy < 0 ? -dy : dy;
      int wy = 4 - ady;
      int ny = y + dy;
      if ((unsigned)ny >= (unsigned)GH) continue;
      for (int dx = -3; dx <= 3; ++dx) {
        if ((dx | dy) == 0) continue;
        int adx = dx < 0 ? -dx : dx;
        int prod = (4 - adx) * wy;
        if (prod < 2) continue;
        if ((pass == 0) != (prod >= 3)) continue;
        int nx = x + dx;
        if ((unsigned)nx >= (unsigned)GW) continue;
        unsigned int npix = (unsigned int)(ny*GW + nx);
        unsigned int nid = map[npix];
        if (nid == ~0u) continue;
        float ns = scores[nid];
        unsigned int nsb = __float_as_uint(ns);
        if (nsb > sb || (nsb == sb && npix < pos)) {   // neighbor outranks me
          unsigned int nh = (ns > 0.95f) ? 1u : 0u;
          row[1 + n] = (unsigned short)(nid | (nh << 15));
          n++;
          if (pass == 0) n3++;
        }
      }
    }
  }
  row[0] = (unsigned short)(n3 | (n << 6) | (high << 12));
}

// single block: fixed-point greedy NMS (stages A/B then C) on LDS state,
// then rank-by-count ordering of final keeps and output write.
// st bits: 1=AB_DEC 2=AB_KEPT 4=C_DEC 8=C_KEPT 16=LOW
__global__ __launch_bounds__(1024) void k_nms(const unsigned int* __restrict__ list,
                                              const float* __restrict__ scores,
                                              const unsigned short* __restrict__ adj,
                                              const unsigned int* __restrict__ mm,
                                              float* __restrict__ out, int nrows) {
  __shared__ unsigned char st[CAP];
  __shared__ unsigned short act[2][CAP];
  __shared__ unsigned long long skeys[KCAP];
  __shared__ unsigned int s_cnt[2];
  __shared__ unsigned int s_k;
  const int tid = threadIdx.x;
  int M = (int)min(mm[0], (unsigned int)CAP);
  for (int i = tid; i < CAP; i += 1024) st[i] = 0;
  for (int i = tid; i < M; i += 1024) act[0][i] = (unsigned short)i;
  if (tid == 0) { s_cnt[0] = (unsigned int)M; s_cnt[1] = 0; s_k = 0; }
  __syncthreads();

  // ---- Stages A (highs: all entries) + B (lows: n3 prefix), one fixed point
  int cur = 0;
  for (int round = 0; round < CAP; ++round) {
    unsigned int cnt = s_cnt[cur];
    if (cnt == 0) break;
    for (unsigned int i = tid; i < cnt; i += 1024) {
      int r = act[cur][i];
      const unsigned short* row = adj + (size_t)r * ADJ_STRIDE;
      unsigned int hdr = row[0];
      unsigned int high = (hdr >> 12) & 1u;
      int n = high ? (int)((hdr >> 6) & 63u) : (int)(hdr & 63u);
      unsigned char lowbit = high ? 0 : 16;
      bool sup = false, und = false;
      for (int k = 1; k <= n; ++k) {
        unsigned int e = row[k];
        if (((e >> 15) & 1u) != high) continue;   // same band only
        unsigned char ps = st[e & 0x1FFFu];
        if (ps & 2) { sup = true; break; }        // kept outranking neighbor
        if (!(ps & 1)) und = true;                // still undecided
      }
      if (sup)          st[r] = (unsigned char)(1 | lowbit);
      else if (!und)    st[r] = (unsigned char)(3 | lowbit);
      else { unsigned int j = atomicAdd(&s_cnt[cur ^ 1], 1u); act[cur ^ 1][j] = (unsigned short)r; }
    }
    __syncthreads();
    if (tid == 0) s_cnt[cur] = 0;
    cur ^= 1;
    __syncthreads();
  }
  __syncthreads();

  // ---- Stage C: AB-kept lows, all entries (inter>=2); kept highs suppress
  if (tid == 0) { s_cnt[0] = 0; s_cnt[1] = 0; }
  __syncthreads();
  for (int i = tid; i < M; i += 1024) {
    unsigned char s0 = st[i];
    if ((s0 & 16) && (s0 & 2)) {
      unsigned int j = atomicAdd(&s_cnt[0], 1u); act[0][j] = (unsigned short)i;
    }
  }
  __syncthreads();
  cur = 0;
  for (int round = 0; round < CAP; ++round) {
    unsigned int cnt = s_cnt[cur];
    if (cnt == 0) break;
    for (unsigned int i = tid; i < cnt; i += 1024) {
      int r = act[cur][i];
      const unsigned short* row = adj + (size_t)r * ADJ_STRIDE;
      unsigned int hdr = row[0];
      int n = (int)((hdr >> 6) & 63u);
      bool sup = false, und = false;
      for (int k = 1; k <= n; ++k) {
        unsigned int e = row[k];
        unsigned char ps = st[e & 0x1FFFu];
        if ((e >> 15) & 1u) {
          if (ps & 2) { sup = true; break; }      // A-kept high always wins
        } else {
          if (!(ps & 2)) continue;                // not B-kept -> not in C set
          if (ps & 8) { sup = true; break; }      // C-kept outranking low
          if (!(ps & 4)) und = true;
        }
      }
      if (sup)          st[r] |= 4;
      else if (!und)    st[r] |= 12;
      else { unsigned int j = atomicAdd(&s_cnt[cur ^ 1], 1u); act[cur ^ 1][j] = (unsigned short)r; }
    }
    __syncthreads();
    if (tid == 0) s_cnt[cur] = 0;
    cur ^= 1;
    __syncthreads();
  }
  __syncthreads();

  // ---- collect final keeps (order irrelevant)
  for (int i = tid; i < M; i += 1024) {
    unsigned char s0 = st[i];
    bool keep = (s0 & 16) ? ((s0 & 8) != 0) : ((s0 & 2) != 0);
    if (keep) {
      unsigned int j = atomicAdd(&s_k, 1u);
      if (j < KCAP) {
        unsigned int pos = list[i];
        unsigned int sb = __float_as_uint(scores[i]);
        skeys[j] = (((unsigned long long)(0xFFFFFFFFu - sb)) << 32) | (unsigned long long)pos;
      }
    }
  }
  __syncthreads();
  unsigned int K = min(s_k, (unsigned int)KCAP);

  // ---- rank-by-count (keys distinct since pos distinct), write rows
  for (unsigned int i = tid; i < K; i += 1024) {
    unsigned long long key = skeys[i];
    unsigned int rank = 0;
    for (unsigned int q = 0; q < K; ++q) rank += (skeys[q] < key) ? 1u : 0u;
    if ((int)rank < nrows) {
      unsigned int pos = (unsigned int)(key & 0xFFFFFFFFu);
      float s = __uint_as_float(0xFFFFFFFFu - (unsigned int)(key >> 32));
      float fx = (float)(pos & 1023), fy = (float)(pos >> 10);
      out[rank*5 + 0] = fx - 2.0f;
      out[rank*5 + 1] = fy - 2.0f;
      out[rank*5 + 2] = fx + 2.0f;
      out[rank*5 + 3] = fy + 2.0f;
      out[rank*5 + 4] = s;
    }
  }
}

extern "C" void kernel_launch(void* const* d_in, const int* in_sizes, int n_in,
                              void* d_out, int out_size, void* d_ws, size_t ws_size,
                              hipStream_t stream) {
  const float* x1 = (const float*)d_in[0];
  const float* x2 = (const float*)d_in[1];
  const float* x3 = (const float*)d_in[2];
  char* ws = (char*)d_ws;
  float* rmap = (float*)ws;                                  // 4MB
  float* Amap = (float*)(ws + (4u << 20));                   // 4MB (reused as map)
  float* Bmap = (float*)(ws + (8u << 20));                   // 4MB
  unsigned int* map = (unsigned int*)(ws + (4u << 20));      // overlays Amap (dead after convx)
  unsigned int* mm  = (unsigned int*)(ws + (12u << 20));
  unsigned int* list = (unsigned int*)(ws + (12u << 20) + 4096u);       // 32KB
  float* scores = (float*)(ws + (12u << 20) + (64u << 10));             // 32KB
  unsigned short* adj = (unsigned short*)(ws + (12u << 20) + (128u << 10)); // 768KB
  float2* pmm = (float2*)(ws + (13u << 20));                 // 8KB
  float* pbmax = (float*)(ws + (13u << 20) + (16u << 10));   // 4KB
  float* out = (float*)d_out;

  k_resid<<<NPIX/4/256, 256, 0, stream>>>((const float4*)x1, (const float4*)x2,
                                          (const float4*)x3, (float4*)rmap, pmm);
  k_reduce1<<<1, 1024, 0, stream>>>(pmm, mm);
  dim3 g2(GW/256, GH);
  k_convy<<<g2, 256, 0, stream>>>(rmap, Amap, mm);
  k_convx<<<GH, 256, 0, stream>>>(Amap, Bmap, pbmax);
  k_reduce2<<<1, 1024, 0, stream>>>(pbmax, mm);
  k_cand<<<NPIX/4/256, 256, 0, stream>>>((const float4*)Bmap, (uint4*)map, list, scores, mm);
  k_adj<<<CAP/256, 256, 0, stream>>>(list, scores, map, mm, adj);
  k_nms<<<1, 1024, 0, stream>>>(list, scores, adj, mm, out, out_size / 5);
}